// Round 2
// baseline (217.585 us; speedup 1.0000x reference)
//
#include <hip/hip_runtime.h>
#include <math.h>

typedef float  f32x4  __attribute__((ext_vector_type(4)));
typedef float  f32x2  __attribute__((ext_vector_type(2)));
typedef short  bf16x8 __attribute__((ext_vector_type(8)));
typedef unsigned short u16x8 __attribute__((ext_vector_type(8)));
typedef unsigned short u16x4 __attribute__((ext_vector_type(4)));

#define B_ROWS 2048
#define D_DIM  512
#define W_DIM  512
#define N_NODES 63
#define N_BINS  64
#define K_TOT   32768   // 64 * 512
#define NSPLIT  8       // 8 l's per z-slot
#define LPS     (N_BINS / NSPLIT)   // 8
#define DEPS    1e-12f

__device__ __forceinline__ unsigned short f2bf(float f) {
    union { float f; unsigned int u; } v; v.f = f;
    unsigned int u = v.u;
    return (unsigned short)((u + 0x7fffu + ((u >> 16) & 1u)) >> 16);
}

__device__ __forceinline__ float sigmoidf_(float z) {
    return 1.0f / (1.0f + expf(-z));
}

__device__ __forceinline__ void load_lds16(const void* g, void* l) {
    __builtin_amdgcn_global_load_lds(
        (const __attribute__((address_space(1))) unsigned int*)g,
        (__attribute__((address_space(3))) unsigned int*)l,
        16, 0, 0);
}

// ---------------- kernel 1: fused prep (dist + xb) AND transpose -----------
__global__ __launch_bounds__(256) void k_pre(
    const float* __restrict__ x, const float* __restrict__ ray,
    const float* __restrict__ w_i, const float* __restrict__ b_i,
    const float* __restrict__ a_i, const int* __restrict__ idx,
    const float* __restrict__ T,
    float* __restrict__ dist, unsigned short* __restrict__ xb,
    unsigned short* __restrict__ Tt)
{
    __shared__ float tile[64][65];
    const int bid = blockIdx.x;
    const int t   = threadIdx.x;

    if (bid < 4096) {
        const int i0 = (bid & 7) * 64;
        const int w0 = ((bid >> 3) & 7) * 64;
        const int l  = bid >> 6;

        const int w4 = (t & 15) * 4;
        const int ir = t >> 4;
        const float* src = T + ((size_t)(l * 512 + i0)) * 512 + w0;
#pragma unroll
        for (int p = 0; p < 4; ++p) {
            int i = ir + p * 16;
            f32x4 v = *(const f32x4*)(src + (size_t)i * 512 + w4);
            tile[i][w4 + 0] = v.x; tile[i][w4 + 1] = v.y;
            tile[i][w4 + 2] = v.z; tile[i][w4 + 3] = v.w;
        }
        __syncthreads();
#pragma unroll
        for (int rep = 0; rep < 2; ++rep) {
            int id = t + rep * 256;
            int w  = id >> 3;
            int c  = id & 7;
            u16x8 o;
#pragma unroll
            for (int j = 0; j < 8; ++j) o[j] = f2bf(tile[c * 8 + j][w]);
            *(u16x8*)(Tt + (size_t)(w0 + w) * K_TOT + l * 512 + i0 + c * 8) = o;
        }
        return;
    }

    const int pb   = bid - 4096;
    const int wid  = t >> 6;
    const int lane = t & 63;
    const int row  = pb * 4 + wid;
    const float* xr = x + (size_t)row * D_DIM;

    float dotv = 0.f, xx = 0.f, rr = 0.f;
#pragma unroll
    for (int j = 0; j < 2; ++j) {
        f32x4 xv = *(const f32x4*)(xr  + j * 256 + lane * 4);
        f32x4 rv = *(const f32x4*)(ray + j * 256 + lane * 4);
        dotv += xv.x * rv.x + xv.y * rv.y + xv.z * rv.z + xv.w * rv.w;
        xx   += xv.x * xv.x + xv.y * xv.y + xv.z * xv.z + xv.w * xv.w;
        rr   += rv.x * rv.x + rv.y * rv.y + rv.z * rv.z + rv.w * rv.w;
        u16x4 o;
        o[0] = f2bf(xv.x); o[1] = f2bf(xv.y); o[2] = f2bf(xv.z); o[3] = f2bf(xv.w);
        *(u16x4*)(xb + (size_t)row * D_DIM + j * 256 + lane * 4) = o;
    }
#pragma unroll
    for (int off = 1; off < 64; off <<= 1) {
        dotv += __shfl_xor(dotv, off, 64);
        xx   += __shfl_xor(xx,   off, 64);
        rr   += __shfl_xor(rr,   off, 64);
    }
    float xn = fmaxf(sqrtf(xx), 1e-8f);
    float rn = fmaxf(sqrtf(rr), 1e-8f);
    float cosv = dotv / (xn * rn);
    cosv = fminf(1.f, fmaxf(-1.f, cosv));
    float angle = acosf(cosv) * 0.31830988618379067f;

    float dec = 0.f;
    if (lane < N_NODES) {
        float sw = sigmoidf_(w_i[lane]);
        float sb = sigmoidf_(b_i[lane]);
        float nf = (0.5f + sw) * angle - sb;
        dec = sigmoidf_(nf * (1.0f + a_i[lane]));
    }

    float p = 1.f;
#pragma unroll
    for (int v = 0; v < 6; ++v) {
        int j = idx[lane * 6 + v];
        int node = (j < N_NODES) ? j : j - N_NODES;
        float d = __shfl(dec, node, 64);
        p *= (j < N_NODES) ? d : (1.0f - d);
    }
    dist[(size_t)row * N_BINS + lane] = p;
}

// ---------------- kernel 2: fat-wave dual-accumulator GEMM -----------------
// BM=256, BN=128, BK=64, 4 waves (2M x 2N), per-wave 128x64 C.
// Fragment-read traffic per tile drops 128->96 KB (each A/B fragment
// shared by only 2 waves) -> LDS-port time ~= MFMA time (balanced).
// Dual accumulator: P = sum_i x*T for current l; at each l boundary
// S += d[m,l]*P, P=0 (exact, replaces rescale + rcp + DEPS clamps).
// 3-deep LDS ring (144 KB), counted vmcnt(12), one barrier per tile.
__global__ __launch_bounds__(256, 1) void k_gemm11(
    const unsigned short* __restrict__ xb, const unsigned short* __restrict__ Tt,
    const float* __restrict__ dist, float* __restrict__ part)
{
    __shared__ unsigned short As[3][256 * 64];   // 96 KB
    __shared__ unsigned short Bs[3][128 * 64];   // 48 KB

    const int b    = blockIdx.x;          // 0..255
    const int z    = b & 7;               // split == XCD
    const int tile = b >> 3;              // 0..31
    const int bm0  = (tile & 7) * 256;
    const int bn0  = (tile >> 3) * 128;
    const int l0   = z * LPS;

    const int t    = threadIdx.x;         // 0..255
    const int lane = t & 63;
    const int wid  = t >> 6;              // 0..3
    const int wm = wid >> 1, wn = wid & 1;
    const int lq = lane >> 4, lr = lane & 15;

    const int srow = t >> 3;              // 0..31
    const int c    = t & 7;

    f32x4 accS[8][4], accP[8][4];
#pragma unroll
    for (int a = 0; a < 8; ++a)
#pragma unroll
        for (int bb = 0; bb < 4; ++bb) {
            accS[a][bb] = (f32x4){0.f, 0.f, 0.f, 0.f};
            accP[a][bb] = (f32x4){0.f, 0.f, 0.f, 0.f};
        }

#define STAGE_A(u_, slot_, g_)                                                \
    {                                                                         \
        const int i0_  = ((u_) & 7) * 64;                                     \
        const int row_ = srow + (g_) * 32;                                    \
        const int cg_  = c ^ (row_ & 7);                                      \
        load_lds16(xb + (size_t)(bm0 + row_) * D_DIM + i0_ + cg_ * 8,         \
                   &As[slot_][row_ * 64 + c * 8]);                            \
    }
#define STAGE_B(u_, slot_, g_)                                                \
    {                                                                         \
        const int l_   = l0 + ((u_) >> 3);                                    \
        const int i0_  = ((u_) & 7) * 64;                                     \
        const int row_ = srow + (g_) * 32;                                    \
        const int cg_  = c ^ (row_ & 7);                                      \
        load_lds16(Tt + (size_t)(bn0 + row_) * K_TOT + (size_t)l_ * 512       \
                       + i0_ + cg_ * 8,                                       \
                   &Bs[slot_][row_ * 64 + c * 8]);                            \
    }

    // prologue: tile 0 -> slot 0, tile 1 -> slot 1 (24 loads in flight)
    STAGE_A(0, 0, 0) STAGE_A(0, 0, 1) STAGE_A(0, 0, 2) STAGE_A(0, 0, 3)
    STAGE_A(0, 0, 4) STAGE_A(0, 0, 5) STAGE_A(0, 0, 6) STAGE_A(0, 0, 7)
    STAGE_B(0, 0, 0) STAGE_B(0, 0, 1) STAGE_B(0, 0, 2) STAGE_B(0, 0, 3)
    STAGE_A(1, 1, 0) STAGE_A(1, 1, 1) STAGE_A(1, 1, 2) STAGE_A(1, 1, 3)
    STAGE_A(1, 1, 4) STAGE_A(1, 1, 5) STAGE_A(1, 1, 6) STAGE_A(1, 1, 7)
    STAGE_B(1, 1, 0) STAGE_B(1, 1, 1) STAGE_B(1, 1, 2) STAGE_B(1, 1, 3)

    int rs = 0;   // read slot = u % 3
    for (int u = 0; u < 64; ++u) {
        // tile boundary: own tile-u loads done, tile-u+1's 12 stay in flight
        if (u < 63) asm volatile("s_waitcnt vmcnt(12)" ::: "memory");
        else        asm volatile("s_waitcnt vmcnt(0)" ::: "memory");
        __builtin_amdgcn_s_barrier();

        const int ws_ = (rs == 0) ? 2 : rs - 1;   // write slot = (u+2)%3
        const bool pf = (u + 2 < 64);

        // ---------------- phase 0 : ks = 0 ----------------
        {
            bf16x8 af[8], bfv[4];
#pragma unroll
            for (int fm = 0; fm < 8; ++fm) {
                int m = wm * 128 + fm * 16 + lr;
                af[fm] = *(const bf16x8*)&As[rs][m * 64 + ((lq ^ (m & 7)) * 8)];
            }
#pragma unroll
            for (int fn = 0; fn < 4; ++fn) {
                int n = wn * 64 + fn * 16 + lr;
                bfv[fn] = *(const bf16x8*)&Bs[rs][n * 64 + ((lq ^ (n & 7)) * 8)];
            }
            if (pf) {
                STAGE_A(u + 2, ws_, 0) STAGE_A(u + 2, ws_, 1)
                STAGE_A(u + 2, ws_, 2) STAGE_A(u + 2, ws_, 3)
                STAGE_A(u + 2, ws_, 4) STAGE_A(u + 2, ws_, 5)
                STAGE_A(u + 2, ws_, 6) STAGE_A(u + 2, ws_, 7)
            }
            // l-boundary fold: S += d[m, l-1] * P, P = 0 (exact dist fold)
            if ((u & 7) == 0 && u > 0) {
                const int lp = l0 + (u >> 3) - 1;
#pragma unroll
                for (int fm = 0; fm < 8; ++fm)
#pragma unroll
                    for (int r = 0; r < 4; ++r) {
                        int m = bm0 + wm * 128 + fm * 16 + lq * 4 + r;
                        float dv = dist[(size_t)m * N_BINS + lp];
#pragma unroll
                        for (int fn = 0; fn < 4; ++fn) {
                            accS[fm][fn][r] += dv * accP[fm][fn][r];
                            accP[fm][fn][r] = 0.f;
                        }
                    }
            }
            __builtin_amdgcn_s_setprio(1);
#pragma unroll
            for (int fm = 0; fm < 8; ++fm)
#pragma unroll
                for (int fn = 0; fn < 4; ++fn)
                    accP[fm][fn] = __builtin_amdgcn_mfma_f32_16x16x32_bf16(
                        af[fm], bfv[fn], accP[fm][fn], 0, 0, 0);
            __builtin_amdgcn_s_setprio(0);
        }
        // ---------------- phase 1 : ks = 1 ----------------
        {
            bf16x8 af[8], bfv[4];
#pragma unroll
            for (int fm = 0; fm < 8; ++fm) {
                int m = wm * 128 + fm * 16 + lr;
                af[fm] = *(const bf16x8*)&As[rs][m * 64 + (((4 + lq) ^ (m & 7)) * 8)];
            }
#pragma unroll
            for (int fn = 0; fn < 4; ++fn) {
                int n = wn * 64 + fn * 16 + lr;
                bfv[fn] = *(const bf16x8*)&Bs[rs][n * 64 + (((4 + lq) ^ (n & 7)) * 8)];
            }
            if (pf) {
                STAGE_B(u + 2, ws_, 0) STAGE_B(u + 2, ws_, 1)
                STAGE_B(u + 2, ws_, 2) STAGE_B(u + 2, ws_, 3)
            }
            __builtin_amdgcn_s_setprio(1);
#pragma unroll
            for (int fm = 0; fm < 8; ++fm)
#pragma unroll
                for (int fn = 0; fn < 4; ++fn)
                    accP[fm][fn] = __builtin_amdgcn_mfma_f32_16x16x32_bf16(
                        af[fm], bfv[fn], accP[fm][fn], 0, 0, 0);
            __builtin_amdgcn_s_setprio(0);
        }

        rs = (rs == 2) ? 0 : rs + 1;
    }
#undef STAGE_A
#undef STAGE_B

    // epilogue: final fold with d[m, l0+7] and store
    const int ll = l0 + LPS - 1;
    float* Cp = part + (size_t)z * (B_ROWS * W_DIM);
#pragma unroll
    for (int fm = 0; fm < 8; ++fm)
#pragma unroll
        for (int r = 0; r < 4; ++r) {
            int m = bm0 + wm * 128 + fm * 16 + lq * 4 + r;
            float dv = dist[(size_t)m * N_BINS + ll];
#pragma unroll
            for (int fn = 0; fn < 4; ++fn) {
                int col = bn0 + wn * 64 + fn * 16 + lr;
                Cp[(size_t)m * W_DIM + col] =
                    accS[fm][fn][r] + dv * accP[fm][fn][r];
            }
        }
}

// ---------------- kernel 3: split reduction --------------------------------
__global__ __launch_bounds__(256) void k_reduce(
    const float* __restrict__ part, float* __restrict__ out, int nsplit)
{
    int i = (blockIdx.x * 256 + threadIdx.x) * 4;
    f32x4 s = *(const f32x4*)(part + i);
    for (int p = 1; p < nsplit; ++p)
        s += *(const f32x4*)(part + (size_t)p * (B_ROWS * W_DIM) + i);
    *(f32x4*)(out + i) = s;
}

// ---------------- fallback GEMM (single-split, direct to out) --------------
__global__ __launch_bounds__(256, 2) void k_gemm_bt(
    const float* __restrict__ x, const float* __restrict__ dist,
    const unsigned short* __restrict__ Tt, float* __restrict__ part,
    int kchunk)
{
    __shared__ unsigned short As[128][72];
    __shared__ unsigned short Bs[128][64];

    const int bm0 = blockIdx.x * 128;
    const int bn0 = blockIdx.y * 128;
    const int kbase = blockIdx.z * kchunk;

    const int lane = threadIdx.x & 63;
    const int wid  = threadIdx.x >> 6;
    const int wm = wid >> 1, wn = wid & 1;
    const int lq = lane >> 4, lr = lane & 15;

    f32x4 acc[4][4];
#pragma unroll
    for (int a = 0; a < 4; ++a)
#pragma unroll
        for (int b = 0; b < 4; ++b)
            acc[a][b] = (f32x4){0.f, 0.f, 0.f, 0.f};

    const int iters = kchunk / 64;
    for (int it = 0; it < iters; ++it) {
        const int k0 = kbase + it * 64;
        const int l  = k0 >> 9;
        const int i0 = k0 & 511;
#pragma unroll
        for (int r2 = 0; r2 < 8; ++r2) {
            int id = threadIdx.x + r2 * 256;
            int m  = id >> 4;
            int kc = id & 15;
            float sc = dist[(size_t)(bm0 + m) * N_BINS + l];
            f32x4 v = *(const f32x4*)(x + (size_t)(bm0 + m) * D_DIM + i0 + kc * 4);
            v *= sc;
            unsigned int p0 = (unsigned int)f2bf(v.x) | ((unsigned int)f2bf(v.y) << 16);
            unsigned int p1 = (unsigned int)f2bf(v.z) | ((unsigned int)f2bf(v.w) << 16);
            unsigned int* dp = (unsigned int*)&As[m][kc * 4];
            dp[0] = p0; dp[1] = p1;
        }
#pragma unroll
        for (int r2 = 0; r2 < 4; ++r2) {
            int id = threadIdx.x + r2 * 256;
            int n  = id >> 3;
            int cc = id & 7;
            int cg = cc ^ (n & 7);
            const u16x8 v = *(const u16x8*)(Tt + (size_t)(bn0 + n) * K_TOT + k0 + cg * 8);
            *(u16x8*)&Bs[n][cc * 8] = v;
        }
        __syncthreads();
#pragma unroll
        for (int ks = 0; ks < 2; ++ks) {
            bf16x8 af[4], bfr[4];
#pragma unroll
            for (int fm = 0; fm < 4; ++fm)
                af[fm] = *(const bf16x8*)&As[wm * 64 + fm * 16 + lr][ks * 32 + lq * 8];
#pragma unroll
            for (int fn = 0; fn < 4; ++fn) {
                int nl = wn * 64 + fn * 16 + lr;
                int cs = (ks * 4 + lq) ^ (nl & 7);
                bfr[fn] = *(const bf16x8*)&Bs[nl][cs * 8];
            }
#pragma unroll
            for (int fm = 0; fm < 4; ++fm)
#pragma unroll
                for (int fn = 0; fn < 4; ++fn)
                    acc[fm][fn] = __builtin_amdgcn_mfma_f32_16x16x32_bf16(
                        af[fm], bfr[fn], acc[fm][fn], 0, 0, 0);
        }
        __syncthreads();
    }

    float* Cp = part + (size_t)blockIdx.z * (B_ROWS * W_DIM);
#pragma unroll
    for (int fm = 0; fm < 4; ++fm)
#pragma unroll
        for (int fn = 0; fn < 4; ++fn)
#pragma unroll
            for (int r = 0; r < 4; ++r) {
                int row = bm0 + wm * 64 + fm * 16 + lq * 4 + r;
                int col = bn0 + wn * 64 + fn * 16 + lr;
                Cp[(size_t)row * W_DIM + col] = acc[fm][fn][r];
            }
}

extern "C" void kernel_launch(void* const* d_in, const int* in_sizes, int n_in,
                              void* d_out, int out_size, void* d_ws, size_t ws_size,
                              hipStream_t stream) {
    const float* x   = (const float*)d_in[0];
    const float* ray = (const float*)d_in[1];
    const float* w_i = (const float*)d_in[2];
    const float* b_i = (const float*)d_in[3];
    const float* a_i = (const float*)d_in[4];
    const float* T   = (const float*)d_in[5];
    const int*   idx = (const int*)d_in[6];
    float* out = (float*)d_out;

    char* ws = (char*)d_ws;
    const size_t distBytes = (size_t)B_ROWS * N_BINS * 4;        // 512 KiB
    const size_t xbBytes   = (size_t)B_ROWS * D_DIM * 2;         // 2 MiB
    const size_t ttBytes   = (size_t)W_DIM * K_TOT * 2;          // 32 MiB
    const size_t partBytes = (size_t)B_ROWS * W_DIM * 4;         // 4 MiB per split

    float*          dist = (float*)ws;
    unsigned short* xb   = (unsigned short*)(ws + distBytes);
    unsigned short* Tt   = (unsigned short*)(ws + distBytes + xbBytes);

    if (ws_size >= distBytes + xbBytes + ttBytes + (size_t)NSPLIT * partBytes) {
        // -------- path A: fat-wave dual-acc pipelined GEMM, NSPLIT=8 ----
        float* part = (float*)(ws + distBytes + xbBytes + ttBytes);

        k_pre<<<4096 + 512, 256, 0, stream>>>(x, ray, w_i, b_i, a_i, idx, T,
                                              dist, xb, Tt);
        k_gemm11<<<256, 256, 0, stream>>>(xb, Tt, dist, part);
        k_reduce<<<(B_ROWS * W_DIM) / (256 * 4), 256, 0, stream>>>(part, out, NSPLIT);
    } else if (ws_size >= distBytes + xbBytes + ttBytes) {
        // -------- path B: single-split direct-to-out --------
        k_pre<<<4096 + 512, 256, 0, stream>>>(x, ray, w_i, b_i, a_i, idx, T,
                                              dist, xb, Tt);
        k_gemm_bt<<<dim3(16, 4, 1), 256, 0, stream>>>(x, dist, Tt, out, K_TOT);
    }
}

// Round 3
// 192.715 us; speedup vs baseline: 1.1291x; 1.1291x over previous
//
#include <hip/hip_runtime.h>
#include <math.h>

typedef float  f32x4  __attribute__((ext_vector_type(4)));
typedef float  f32x2  __attribute__((ext_vector_type(2)));
typedef short  bf16x8 __attribute__((ext_vector_type(8)));
typedef unsigned short u16x8 __attribute__((ext_vector_type(8)));
typedef unsigned short u16x4 __attribute__((ext_vector_type(4)));

#define B_ROWS 2048
#define D_DIM  512
#define W_DIM  512
#define N_NODES 63
#define N_BINS  64
#define K_TOT   32768   // 64 * 512
#define NSPLIT  8       // 8 l's per z-slot
#define LPS     (N_BINS / NSPLIT)   // 8
#define DEPS    1e-12f

__device__ __forceinline__ unsigned short f2bf(float f) {
    union { float f; unsigned int u; } v; v.f = f;
    unsigned int u = v.u;
    return (unsigned short)((u + 0x7fffu + ((u >> 16) & 1u)) >> 16);
}

__device__ __forceinline__ float sigmoidf_(float z) {
    return 1.0f / (1.0f + expf(-z));
}

__device__ __forceinline__ void load_lds16(const void* g, void* l) {
    __builtin_amdgcn_global_load_lds(
        (const __attribute__((address_space(1))) unsigned int*)g,
        (__attribute__((address_space(3))) unsigned int*)l,
        16, 0, 0);
}

// ---------------- kernel 1: fused prep (dist + xb) AND transpose -----------
__global__ __launch_bounds__(256) void k_pre(
    const float* __restrict__ x, const float* __restrict__ ray,
    const float* __restrict__ w_i, const float* __restrict__ b_i,
    const float* __restrict__ a_i, const int* __restrict__ idx,
    const float* __restrict__ T,
    float* __restrict__ dist, unsigned short* __restrict__ xb,
    unsigned short* __restrict__ Tt)
{
    __shared__ float tile[64][65];
    const int bid = blockIdx.x;
    const int t   = threadIdx.x;

    if (bid < 4096) {
        const int i0 = (bid & 7) * 64;
        const int w0 = ((bid >> 3) & 7) * 64;
        const int l  = bid >> 6;

        const int w4 = (t & 15) * 4;
        const int ir = t >> 4;
        const float* src = T + ((size_t)(l * 512 + i0)) * 512 + w0;
#pragma unroll
        for (int p = 0; p < 4; ++p) {
            int i = ir + p * 16;
            f32x4 v = *(const f32x4*)(src + (size_t)i * 512 + w4);
            tile[i][w4 + 0] = v.x; tile[i][w4 + 1] = v.y;
            tile[i][w4 + 2] = v.z; tile[i][w4 + 3] = v.w;
        }
        __syncthreads();
#pragma unroll
        for (int rep = 0; rep < 2; ++rep) {
            int id = t + rep * 256;
            int w  = id >> 3;
            int c  = id & 7;
            u16x8 o;
#pragma unroll
            for (int j = 0; j < 8; ++j) o[j] = f2bf(tile[c * 8 + j][w]);
            *(u16x8*)(Tt + (size_t)(w0 + w) * K_TOT + l * 512 + i0 + c * 8) = o;
        }
        return;
    }

    const int pb   = bid - 4096;
    const int wid  = t >> 6;
    const int lane = t & 63;
    const int row  = pb * 4 + wid;
    const float* xr = x + (size_t)row * D_DIM;

    float dotv = 0.f, xx = 0.f, rr = 0.f;
#pragma unroll
    for (int j = 0; j < 2; ++j) {
        f32x4 xv = *(const f32x4*)(xr  + j * 256 + lane * 4);
        f32x4 rv = *(const f32x4*)(ray + j * 256 + lane * 4);
        dotv += xv.x * rv.x + xv.y * rv.y + xv.z * rv.z + xv.w * rv.w;
        xx   += xv.x * xv.x + xv.y * xv.y + xv.z * xv.z + xv.w * xv.w;
        rr   += rv.x * rv.x + rv.y * rv.y + rv.z * rv.z + rv.w * rv.w;
        u16x4 o;
        o[0] = f2bf(xv.x); o[1] = f2bf(xv.y); o[2] = f2bf(xv.z); o[3] = f2bf(xv.w);
        *(u16x4*)(xb + (size_t)row * D_DIM + j * 256 + lane * 4) = o;
    }
#pragma unroll
    for (int off = 1; off < 64; off <<= 1) {
        dotv += __shfl_xor(dotv, off, 64);
        xx   += __shfl_xor(xx,   off, 64);
        rr   += __shfl_xor(rr,   off, 64);
    }
    float xn = fmaxf(sqrtf(xx), 1e-8f);
    float rn = fmaxf(sqrtf(rr), 1e-8f);
    float cosv = dotv / (xn * rn);
    cosv = fminf(1.f, fmaxf(-1.f, cosv));
    float angle = acosf(cosv) * 0.31830988618379067f;

    float dec = 0.f;
    if (lane < N_NODES) {
        float sw = sigmoidf_(w_i[lane]);
        float sb = sigmoidf_(b_i[lane]);
        float nf = (0.5f + sw) * angle - sb;
        dec = sigmoidf_(nf * (1.0f + a_i[lane]));
    }

    float p = 1.f;
#pragma unroll
    for (int v = 0; v < 6; ++v) {
        int j = idx[lane * 6 + v];
        int node = (j < N_NODES) ? j : j - N_NODES;
        float d = __shfl(dec, node, 64);
        p *= (j < N_NODES) ? d : (1.0f - d);
    }
    dist[(size_t)row * N_BINS + lane] = p;
}

// ---------------- kernel 2: wave-pair split-K pipelined GEMM ---------------
// BM=256, BN=128, BK=64, 8 waves. Wave = (kh, pm, pn): pair (pm,pn) owns a
// 128x64 C-subtile; kh=0/1 waves cover ks=0/1 of each K-tile. Fragment
// reads drop to 96 KB/tile at 2 waves/SIMD (round-2 traffic at round-1
// occupancy). dist slab staged to LDS in prologue -> rescale/epilogue do
// NOT touch vmcnt (no prefetch drain every 8th tile). Template-style
// phase sandwich: reads -> barrier -> lgkmcnt(0) -> setprio MFMA -> barrier.
// Pair partials combine via LDS in epilogue.
__global__ __launch_bounds__(512, 2) void k_gemm12(
    const unsigned short* __restrict__ xb, const unsigned short* __restrict__ Tt,
    const float* __restrict__ dist, float* __restrict__ part)
{
    __shared__ unsigned short As[3][256 * 64];   // 96 KB
    __shared__ unsigned short Bs[3][128 * 64];   // 48 KB
    __shared__ float distS[256 * 8];             // 8 KB  (152 KB total)

    const int b    = blockIdx.x;          // 0..255
    const int z    = b & 7;               // split == XCD
    const int tile = b >> 3;              // 0..31
    const int bm0  = (tile & 7) * 256;
    const int bn0  = (tile >> 3) * 128;
    const int l0   = z * LPS;

    const int t    = threadIdx.x;         // 0..511
    const int lane = t & 63;
    const int wid  = t >> 6;              // 0..7
    const int kh   = wid >> 2;            // K-half of the pair
    const int pm   = (wid >> 1) & 1;      // M-half
    const int pn   = wid & 1;             // N-half
    const int lq = lane >> 4, lr = lane & 15;

    const int srow = t >> 3;              // 0..63
    const int c    = t & 7;

    f32x4 acc[8][4];
#pragma unroll
    for (int a = 0; a < 8; ++a)
#pragma unroll
        for (int bb = 0; bb < 4; ++bb)
            acc[a][bb] = (f32x4){0.f, 0.f, 0.f, 0.f};

#define STAGE_A(u_, slot_, g_)                                                \
    {                                                                         \
        const int i0_  = ((u_) & 7) * 64;                                     \
        const int row_ = srow + (g_) * 64;                                    \
        const int cg_  = c ^ (row_ & 7);                                      \
        load_lds16(xb + (size_t)(bm0 + row_) * D_DIM + i0_ + cg_ * 8,         \
                   &As[slot_][row_ * 64 + c * 8]);                            \
    }
#define STAGE_B(u_, slot_, g_)                                                \
    {                                                                         \
        const int l_   = l0 + ((u_) >> 3);                                    \
        const int i0_  = ((u_) & 7) * 64;                                     \
        const int row_ = srow + (g_) * 64;                                    \
        const int cg_  = c ^ (row_ & 7);                                      \
        load_lds16(Tt + (size_t)(bn0 + row_) * K_TOT + (size_t)l_ * 512       \
                       + i0_ + cg_ * 8,                                       \
                   &Bs[slot_][row_ * 64 + c * 8]);                            \
    }

    // prologue: dist slab first (oldest), then tiles 0,1 (13 loads in flight)
    {
        const int dr = t >> 1, dh = t & 1;
        load_lds16(dist + (size_t)(bm0 + dr) * N_BINS + l0 + dh * 4,
                   &distS[dr * 8 + dh * 4]);
    }
    STAGE_A(0, 0, 0) STAGE_A(0, 0, 1) STAGE_A(0, 0, 2) STAGE_A(0, 0, 3)
    STAGE_B(0, 0, 0) STAGE_B(0, 0, 1)
    STAGE_A(1, 1, 0) STAGE_A(1, 1, 1) STAGE_A(1, 1, 2) STAGE_A(1, 1, 3)
    STAGE_B(1, 1, 0) STAGE_B(1, 1, 1)

    const int ko = kh * 4;   // k-chunk base for this wave's K-half

    int rs = 0;   // read slot = u % 3
    for (int u = 0; u < 64; ++u) {
        // boundary: tile-u loads (+dist at u=0) done; tile-u+1's 6 in flight
        if (u < 63) asm volatile("s_waitcnt vmcnt(6)" ::: "memory");
        else        asm volatile("s_waitcnt vmcnt(0)" ::: "memory");
        __builtin_amdgcn_s_barrier();

        // segment-boundary rescale: acc *= d[l-1]/d[l]   (LDS-side reads)
        if ((u & 7) == 0 && u > 0) {
            const int li = (u >> 3) - 1;   // 0..6
#pragma unroll
            for (int fm = 0; fm < 8; ++fm)
#pragma unroll
                for (int r = 0; r < 4; ++r) {
                    int ml = pm * 128 + fm * 16 + lq * 4 + r;
                    float d0 = distS[ml * 8 + li];
                    float d1 = distS[ml * 8 + li + 1];
                    float dp = fmaxf(d0, DEPS);
                    float dn = fmaxf(d1, DEPS);
                    float ratio = dp * __builtin_amdgcn_rcpf(dn);
#pragma unroll
                    for (int fn = 0; fn < 4; ++fn)
                        acc[fm][fn][r] *= ratio;
                }
        }

        const int ws_ = (rs == 0) ? 2 : rs - 1;   // write slot = (u+2)%3
        const bool pf = (u + 2 < 64);

        bf16x8 af[8], bfv[4];
        // ---------------- phase 0 : fn 0..1 ----------------
#pragma unroll
        for (int fm = 0; fm < 8; ++fm) {
            int m = pm * 128 + fm * 16 + lr;
            af[fm] = *(const bf16x8*)&As[rs][m * 64 + (((ko + lq) ^ (m & 7)) * 8)];
        }
#pragma unroll
        for (int fn = 0; fn < 2; ++fn) {
            int n = pn * 64 + fn * 16 + lr;
            bfv[fn] = *(const bf16x8*)&Bs[rs][n * 64 + (((ko + lq) ^ (n & 7)) * 8)];
        }
        if (pf) { STAGE_A(u + 2, ws_, 0) STAGE_A(u + 2, ws_, 1) STAGE_A(u + 2, ws_, 2) }
        __builtin_amdgcn_s_barrier();
        asm volatile("s_waitcnt lgkmcnt(0)" ::: "memory");
        __builtin_amdgcn_sched_barrier(0);
        __builtin_amdgcn_s_setprio(1);
#pragma unroll
        for (int fm = 0; fm < 8; ++fm)
#pragma unroll
            for (int fn = 0; fn < 2; ++fn)
                acc[fm][fn] = __builtin_amdgcn_mfma_f32_16x16x32_bf16(
                    af[fm], bfv[fn], acc[fm][fn], 0, 0, 0);
        __builtin_amdgcn_s_setprio(0);
        __builtin_amdgcn_s_barrier();

        // ---------------- phase 1 : fn 2..3 ----------------
#pragma unroll
        for (int fn = 2; fn < 4; ++fn) {
            int n = pn * 64 + fn * 16 + lr;
            bfv[fn] = *(const bf16x8*)&Bs[rs][n * 64 + (((ko + lq) ^ (n & 7)) * 8)];
        }
        if (pf) { STAGE_A(u + 2, ws_, 3) STAGE_B(u + 2, ws_, 0) STAGE_B(u + 2, ws_, 1) }
        __builtin_amdgcn_s_barrier();
        asm volatile("s_waitcnt lgkmcnt(0)" ::: "memory");
        __builtin_amdgcn_sched_barrier(0);
        __builtin_amdgcn_s_setprio(1);
#pragma unroll
        for (int fm = 0; fm < 8; ++fm)
#pragma unroll
            for (int fn = 2; fn < 4; ++fn)
                acc[fm][fn] = __builtin_amdgcn_mfma_f32_16x16x32_bf16(
                    af[fm], bfv[fn], acc[fm][fn], 0, 0, 0);
        __builtin_amdgcn_s_setprio(0);
        // next iteration's boundary barrier closes this phase

        rs = (rs == 2) ? 0 : rs + 1;
    }
#undef STAGE_A
#undef STAGE_B

    // ---------------- epilogue: pair-combine via LDS, fold d[last] ---------
    __syncthreads();   // all reads of the ring done; safe to overlay

    const int pairid = pm * 2 + pn;
    float* dump = (pairid < 3) ? ((float*)&As[0][0] + pairid * 8192)
                               : (float*)&Bs[0][0];

    if (kh == 1) {
#pragma unroll
        for (int fm = 0; fm < 8; ++fm)
#pragma unroll
            for (int fn = 0; fn < 4; ++fn)
                *(f32x4*)&dump[((fm * 4 + fn) * 64 + lane) * 4] = acc[fm][fn];
    }
    __syncthreads();
    if (kh == 0) {
        float* Cp = part + (size_t)z * (B_ROWS * W_DIM);
#pragma unroll
        for (int fm = 0; fm < 8; ++fm)
#pragma unroll
            for (int r = 0; r < 4; ++r) {
                int ml = pm * 128 + fm * 16 + lq * 4 + r;
                int m  = bm0 + ml;
                float dv = distS[ml * 8 + 7];
#pragma unroll
                for (int fn = 0; fn < 4; ++fn) {
                    f32x4 other = *(const f32x4*)&dump[((fm * 4 + fn) * 64 + lane) * 4];
                    int col = bn0 + pn * 64 + fn * 16 + lr;
                    Cp[(size_t)m * W_DIM + col] =
                        (acc[fm][fn][r] + other[r]) * dv;
                }
            }
    }
}

// ---------------- kernel 3: split reduction --------------------------------
__global__ __launch_bounds__(256) void k_reduce(
    const float* __restrict__ part, float* __restrict__ out, int nsplit)
{
    int i = (blockIdx.x * 256 + threadIdx.x) * 4;
    f32x4 s = *(const f32x4*)(part + i);
    for (int p = 1; p < nsplit; ++p)
        s += *(const f32x4*)(part + (size_t)p * (B_ROWS * W_DIM) + i);
    *(f32x4*)(out + i) = s;
}

// ---------------- fallback GEMM (single-split, direct to out) --------------
__global__ __launch_bounds__(256, 2) void k_gemm_bt(
    const float* __restrict__ x, const float* __restrict__ dist,
    const unsigned short* __restrict__ Tt, float* __restrict__ part,
    int kchunk)
{
    __shared__ unsigned short As[128][72];
    __shared__ unsigned short Bs[128][64];

    const int bm0 = blockIdx.x * 128;
    const int bn0 = blockIdx.y * 128;
    const int kbase = blockIdx.z * kchunk;

    const int lane = threadIdx.x & 63;
    const int wid  = threadIdx.x >> 6;
    const int wm = wid >> 1, wn = wid & 1;
    const int lq = lane >> 4, lr = lane & 15;

    f32x4 acc[4][4];
#pragma unroll
    for (int a = 0; a < 4; ++a)
#pragma unroll
        for (int b = 0; b < 4; ++b)
            acc[a][b] = (f32x4){0.f, 0.f, 0.f, 0.f};

    const int iters = kchunk / 64;
    for (int it = 0; it < iters; ++it) {
        const int k0 = kbase + it * 64;
        const int l  = k0 >> 9;
        const int i0 = k0 & 511;
#pragma unroll
        for (int r2 = 0; r2 < 8; ++r2) {
            int id = threadIdx.x + r2 * 256;
            int m  = id >> 4;
            int kc = id & 15;
            float sc = dist[(size_t)(bm0 + m) * N_BINS + l];
            f32x4 v = *(const f32x4*)(x + (size_t)(bm0 + m) * D_DIM + i0 + kc * 4);
            v *= sc;
            unsigned int p0 = (unsigned int)f2bf(v.x) | ((unsigned int)f2bf(v.y) << 16);
            unsigned int p1 = (unsigned int)f2bf(v.z) | ((unsigned int)f2bf(v.w) << 16);
            unsigned int* dp = (unsigned int*)&As[m][kc * 4];
            dp[0] = p0; dp[1] = p1;
        }
#pragma unroll
        for (int r2 = 0; r2 < 4; ++r2) {
            int id = threadIdx.x + r2 * 256;
            int n  = id >> 3;
            int cc = id & 7;
            int cg = cc ^ (n & 7);
            const u16x8 v = *(const u16x8*)(Tt + (size_t)(bn0 + n) * K_TOT + k0 + cg * 8);
            *(u16x8*)&Bs[n][cc * 8] = v;
        }
        __syncthreads();
#pragma unroll
        for (int ks = 0; ks < 2; ++ks) {
            bf16x8 af[4], bfr[4];
#pragma unroll
            for (int fm = 0; fm < 4; ++fm)
                af[fm] = *(const bf16x8*)&As[wm * 64 + fm * 16 + lr][ks * 32 + lq * 8];
#pragma unroll
            for (int fn = 0; fn < 4; ++fn) {
                int nl = wn * 64 + fn * 16 + lr;
                int cs = (ks * 4 + lq) ^ (nl & 7);
                bfr[fn] = *(const bf16x8*)&Bs[nl][cs * 8];
            }
#pragma unroll
            for (int fm = 0; fm < 4; ++fm)
#pragma unroll
                for (int fn = 0; fn < 4; ++fn)
                    acc[fm][fn] = __builtin_amdgcn_mfma_f32_16x16x32_bf16(
                        af[fm], bfr[fn], acc[fm][fn], 0, 0, 0);
        }
        __syncthreads();
    }

    float* Cp = part + (size_t)blockIdx.z * (B_ROWS * W_DIM);
#pragma unroll
    for (int fm = 0; fm < 4; ++fm)
#pragma unroll
        for (int fn = 0; fn < 4; ++fn)
#pragma unroll
            for (int r = 0; r < 4; ++r) {
                int row = bm0 + wm * 64 + fm * 16 + lq * 4 + r;
                int col = bn0 + wn * 64 + fn * 16 + lr;
                Cp[(size_t)row * W_DIM + col] = acc[fm][fn][r];
            }
}

extern "C" void kernel_launch(void* const* d_in, const int* in_sizes, int n_in,
                              void* d_out, int out_size, void* d_ws, size_t ws_size,
                              hipStream_t stream) {
    const float* x   = (const float*)d_in[0];
    const float* ray = (const float*)d_in[1];
    const float* w_i = (const float*)d_in[2];
    const float* b_i = (const float*)d_in[3];
    const float* a_i = (const float*)d_in[4];
    const float* T   = (const float*)d_in[5];
    const int*   idx = (const int*)d_in[6];
    float* out = (float*)d_out;

    char* ws = (char*)d_ws;
    const size_t distBytes = (size_t)B_ROWS * N_BINS * 4;        // 512 KiB
    const size_t xbBytes   = (size_t)B_ROWS * D_DIM * 2;         // 2 MiB
    const size_t ttBytes   = (size_t)W_DIM * K_TOT * 2;          // 32 MiB
    const size_t partBytes = (size_t)B_ROWS * W_DIM * 4;         // 4 MiB per split

    float*          dist = (float*)ws;
    unsigned short* xb   = (unsigned short*)(ws + distBytes);
    unsigned short* Tt   = (unsigned short*)(ws + distBytes + xbBytes);

    if (ws_size >= distBytes + xbBytes + ttBytes + (size_t)NSPLIT * partBytes) {
        // -------- path A: wave-pair split-K pipelined GEMM, NSPLIT=8 ----
        float* part = (float*)(ws + distBytes + xbBytes + ttBytes);

        k_pre<<<4096 + 512, 256, 0, stream>>>(x, ray, w_i, b_i, a_i, idx, T,
                                              dist, xb, Tt);
        k_gemm12<<<256, 512, 0, stream>>>(xb, Tt, dist, part);
        k_reduce<<<(B_ROWS * W_DIM) / (256 * 4), 256, 0, stream>>>(part, out, NSPLIT);
    } else if (ws_size >= distBytes + xbBytes + ttBytes) {
        // -------- path B: single-split direct-to-out --------
        k_pre<<<4096 + 512, 256, 0, stream>>>(x, ray, w_i, b_i, a_i, idx, T,
                                              dist, xb, Tt);
        k_gemm_bt<<<dim3(16, 4, 1), 256, 0, stream>>>(x, dist, Tt, out, K_TOT);
    }
}

// Round 4
// 190.095 us; speedup vs baseline: 1.1446x; 1.0138x over previous
//
#include <hip/hip_runtime.h>
#include <math.h>

typedef float  f32x4  __attribute__((ext_vector_type(4)));
typedef float  f32x2  __attribute__((ext_vector_type(2)));
typedef short  bf16x8 __attribute__((ext_vector_type(8)));
typedef unsigned short u16x8 __attribute__((ext_vector_type(8)));
typedef unsigned short u16x4 __attribute__((ext_vector_type(4)));

#define B_ROWS 2048
#define D_DIM  512
#define W_DIM  512
#define N_NODES 63
#define N_BINS  64
#define K_TOT   32768   // 64 * 512
#define NSPLIT  8       // 8 l's per z-slot
#define LPS     (N_BINS / NSPLIT)   // 8
#define DEPS    1e-12f

__device__ __forceinline__ unsigned short f2bf(float f) {
    union { float f; unsigned int u; } v; v.f = f;
    unsigned int u = v.u;
    return (unsigned short)((u + 0x7fffu + ((u >> 16) & 1u)) >> 16);
}

__device__ __forceinline__ float sigmoidf_(float z) {
    return 1.0f / (1.0f + expf(-z));
}

__device__ __forceinline__ void load_lds16(const void* g, void* l) {
    __builtin_amdgcn_global_load_lds(
        (const __attribute__((address_space(1))) unsigned int*)g,
        (__attribute__((address_space(3))) unsigned int*)l,
        16, 0, 0);
}

// ---------------- kernel 1: fused prep (dist + xb) AND transpose -----------
__global__ __launch_bounds__(256) void k_pre(
    const float* __restrict__ x, const float* __restrict__ ray,
    const float* __restrict__ w_i, const float* __restrict__ b_i,
    const float* __restrict__ a_i, const int* __restrict__ idx,
    const float* __restrict__ T,
    float* __restrict__ dist, unsigned short* __restrict__ xb,
    unsigned short* __restrict__ Tt)
{
    __shared__ float tile[64][65];
    const int bid = blockIdx.x;
    const int t   = threadIdx.x;

    if (bid < 4096) {
        const int i0 = (bid & 7) * 64;
        const int w0 = ((bid >> 3) & 7) * 64;
        const int l  = bid >> 6;

        const int w4 = (t & 15) * 4;
        const int ir = t >> 4;
        const float* src = T + ((size_t)(l * 512 + i0)) * 512 + w0;
#pragma unroll
        for (int p = 0; p < 4; ++p) {
            int i = ir + p * 16;
            f32x4 v = *(const f32x4*)(src + (size_t)i * 512 + w4);
            tile[i][w4 + 0] = v.x; tile[i][w4 + 1] = v.y;
            tile[i][w4 + 2] = v.z; tile[i][w4 + 3] = v.w;
        }
        __syncthreads();
#pragma unroll
        for (int rep = 0; rep < 2; ++rep) {
            int id = t + rep * 256;
            int w  = id >> 3;
            int c  = id & 7;
            u16x8 o;
#pragma unroll
            for (int j = 0; j < 8; ++j) o[j] = f2bf(tile[c * 8 + j][w]);
            *(u16x8*)(Tt + (size_t)(w0 + w) * K_TOT + l * 512 + i0 + c * 8) = o;
        }
        return;
    }

    const int pb   = bid - 4096;
    const int wid  = t >> 6;
    const int lane = t & 63;
    const int row  = pb * 4 + wid;
    const float* xr = x + (size_t)row * D_DIM;

    float dotv = 0.f, xx = 0.f, rr = 0.f;
#pragma unroll
    for (int j = 0; j < 2; ++j) {
        f32x4 xv = *(const f32x4*)(xr  + j * 256 + lane * 4);
        f32x4 rv = *(const f32x4*)(ray + j * 256 + lane * 4);
        dotv += xv.x * rv.x + xv.y * rv.y + xv.z * rv.z + xv.w * rv.w;
        xx   += xv.x * xv.x + xv.y * xv.y + xv.z * xv.z + xv.w * xv.w;
        rr   += rv.x * rv.x + rv.y * rv.y + rv.z * rv.z + rv.w * rv.w;
        u16x4 o;
        o[0] = f2bf(xv.x); o[1] = f2bf(xv.y); o[2] = f2bf(xv.z); o[3] = f2bf(xv.w);
        *(u16x4*)(xb + (size_t)row * D_DIM + j * 256 + lane * 4) = o;
    }
#pragma unroll
    for (int off = 1; off < 64; off <<= 1) {
        dotv += __shfl_xor(dotv, off, 64);
        xx   += __shfl_xor(xx,   off, 64);
        rr   += __shfl_xor(rr,   off, 64);
    }
    float xn = fmaxf(sqrtf(xx), 1e-8f);
    float rn = fmaxf(sqrtf(rr), 1e-8f);
    float cosv = dotv / (xn * rn);
    cosv = fminf(1.f, fmaxf(-1.f, cosv));
    float angle = acosf(cosv) * 0.31830988618379067f;

    float dec = 0.f;
    if (lane < N_NODES) {
        float sw = sigmoidf_(w_i[lane]);
        float sb = sigmoidf_(b_i[lane]);
        float nf = (0.5f + sw) * angle - sb;
        dec = sigmoidf_(nf * (1.0f + a_i[lane]));
    }

    float p = 1.f;
#pragma unroll
    for (int v = 0; v < 6; ++v) {
        int j = idx[lane * 6 + v];
        int node = (j < N_NODES) ? j : j - N_NODES;
        float d = __shfl(dec, node, 64);
        p *= (j < N_NODES) ? d : (1.0f - d);
    }
    dist[(size_t)row * N_BINS + lane] = p;
}

// ---------------- kernel 2: wave-pair split-K, 1-barrier schedule ----------
// BM=256, BN=128, BK=64, 8 waves = (kh, pm, pn); pair (pm,pn) owns a
// 128x64 C-subtile, kh=0/1 cover the two K-halves of each tile.
// Fragment reads = 96 KB/tile at 2 waves/SIMD. ONE boundary barrier per
// tile (round-1 style): no lgkmcnt(0)/sched_barrier sandwich, so waves
// skew and overlap reads with MFMA across the SIMD. distS staged via
// global_load_lds in the prologue -> rescale/epilogue never touch vmcnt.
// 3-deep LDS ring, counted vmcnt(6); pair-combine via LDS in epilogue.
__global__ __launch_bounds__(512, 2) void k_gemm13(
    const unsigned short* __restrict__ xb, const unsigned short* __restrict__ Tt,
    const float* __restrict__ dist, float* __restrict__ part)
{
    __shared__ unsigned short As[3][256 * 64];   // 96 KB
    __shared__ unsigned short Bs[3][128 * 64];   // 48 KB
    __shared__ float distS[256 * 8];             // 8 KB  (152 KB total)

    const int b    = blockIdx.x;          // 0..255
    const int z    = b & 7;               // split == XCD
    const int tile = b >> 3;              // 0..31
    const int bm0  = (tile & 7) * 256;
    const int bn0  = (tile >> 3) * 128;
    const int l0   = z * LPS;

    const int t    = threadIdx.x;         // 0..511
    const int lane = t & 63;
    const int wid  = t >> 6;              // 0..7
    const int kh   = wid >> 2;            // K-half of the pair
    const int pm   = (wid >> 1) & 1;      // M-half
    const int pn   = wid & 1;             // N-half
    const int lq = lane >> 4, lr = lane & 15;

    const int srow = t >> 3;              // 0..63
    const int c    = t & 7;

    f32x4 acc[8][4];
#pragma unroll
    for (int a = 0; a < 8; ++a)
#pragma unroll
        for (int bb = 0; bb < 4; ++bb)
            acc[a][bb] = (f32x4){0.f, 0.f, 0.f, 0.f};

#define STAGE_A(u_, slot_, g_)                                                \
    {                                                                         \
        const int i0_  = ((u_) & 7) * 64;                                     \
        const int row_ = srow + (g_) * 64;                                    \
        const int cg_  = c ^ (row_ & 7);                                      \
        load_lds16(xb + (size_t)(bm0 + row_) * D_DIM + i0_ + cg_ * 8,         \
                   &As[slot_][row_ * 64 + c * 8]);                            \
    }
#define STAGE_B(u_, slot_, g_)                                                \
    {                                                                         \
        const int l_   = l0 + ((u_) >> 3);                                    \
        const int i0_  = ((u_) & 7) * 64;                                     \
        const int row_ = srow + (g_) * 64;                                    \
        const int cg_  = c ^ (row_ & 7);                                      \
        load_lds16(Tt + (size_t)(bn0 + row_) * K_TOT + (size_t)l_ * 512       \
                       + i0_ + cg_ * 8,                                       \
                   &Bs[slot_][row_ * 64 + c * 8]);                            \
    }

    // prologue: dist slab first (oldest), then tiles 0,1 (13 loads in flight)
    {
        const int dr = t >> 1, dh = t & 1;
        load_lds16(dist + (size_t)(bm0 + dr) * N_BINS + l0 + dh * 4,
                   &distS[dr * 8 + dh * 4]);
    }
    STAGE_A(0, 0, 0) STAGE_A(0, 0, 1) STAGE_A(0, 0, 2) STAGE_A(0, 0, 3)
    STAGE_B(0, 0, 0) STAGE_B(0, 0, 1)
    STAGE_A(1, 1, 0) STAGE_A(1, 1, 1) STAGE_A(1, 1, 2) STAGE_A(1, 1, 3)
    STAGE_B(1, 1, 0) STAGE_B(1, 1, 1)

    const int ko = kh * 4;   // k-chunk base for this wave's K-half

    int rs = 0;   // read slot = u % 3
    for (int u = 0; u < 64; ++u) {
        // boundary: tile-u loads (+dist at u=0) done; tile-u+1's 6 in flight
        if (u < 63) asm volatile("s_waitcnt vmcnt(6)" ::: "memory");
        else        asm volatile("s_waitcnt vmcnt(0)" ::: "memory");
        __builtin_amdgcn_s_barrier();

        // segment-boundary rescale: acc *= d[l-1]/d[l]   (LDS-side reads)
        if ((u & 7) == 0 && u > 0) {
            const int li = (u >> 3) - 1;   // 0..6
#pragma unroll
            for (int fm = 0; fm < 8; ++fm)
#pragma unroll
                for (int r = 0; r < 4; ++r) {
                    int ml = pm * 128 + fm * 16 + lq * 4 + r;
                    float d0 = distS[ml * 8 + li];
                    float d1 = distS[ml * 8 + li + 1];
                    float dp = fmaxf(d0, DEPS);
                    float dn = fmaxf(d1, DEPS);
                    float ratio = dp * __builtin_amdgcn_rcpf(dn);
#pragma unroll
                    for (int fn = 0; fn < 4; ++fn)
                        acc[fm][fn][r] *= ratio;
                }
        }

        const int ws_ = (rs == 0) ? 2 : rs - 1;   // write slot = (u+2)%3
        const bool pf = (u + 2 < 64);

        bf16x8 af[8], bfv[4];
#pragma unroll
        for (int fm = 0; fm < 8; ++fm) {
            int m = pm * 128 + fm * 16 + lr;
            af[fm] = *(const bf16x8*)&As[rs][m * 64 + (((ko + lq) ^ (m & 7)) * 8)];
        }
        if (pf) { STAGE_A(u + 2, ws_, 0) STAGE_A(u + 2, ws_, 1) STAGE_A(u + 2, ws_, 2) }
#pragma unroll
        for (int fn = 0; fn < 4; ++fn) {
            int n = pn * 64 + fn * 16 + lr;
            bfv[fn] = *(const bf16x8*)&Bs[rs][n * 64 + (((ko + lq) ^ (n & 7)) * 8)];
        }
        if (pf) { STAGE_A(u + 2, ws_, 3) STAGE_B(u + 2, ws_, 0) STAGE_B(u + 2, ws_, 1) }

        __builtin_amdgcn_s_setprio(1);
#pragma unroll
        for (int fm = 0; fm < 8; ++fm)
#pragma unroll
            for (int fn = 0; fn < 4; ++fn)
                acc[fm][fn] = __builtin_amdgcn_mfma_f32_16x16x32_bf16(
                    af[fm], bfv[fn], acc[fm][fn], 0, 0, 0);
        __builtin_amdgcn_s_setprio(0);

        rs = (rs == 2) ? 0 : rs + 1;
    }
#undef STAGE_A
#undef STAGE_B

    // ---------------- epilogue: pair-combine via LDS, fold d[last] ---------
    __syncthreads();   // all reads of the ring done; safe to overlay

    const int pairid = pm * 2 + pn;
    float* dump = (pairid < 3) ? ((float*)&As[0][0] + pairid * 8192)
                               : (float*)&Bs[0][0];

    if (kh == 1) {
#pragma unroll
        for (int fm = 0; fm < 8; ++fm)
#pragma unroll
            for (int fn = 0; fn < 4; ++fn)
                *(f32x4*)&dump[((fm * 4 + fn) * 64 + lane) * 4] = acc[fm][fn];
    }
    __syncthreads();
    if (kh == 0) {
        float* Cp = part + (size_t)z * (B_ROWS * W_DIM);
#pragma unroll
        for (int fm = 0; fm < 8; ++fm)
#pragma unroll
            for (int r = 0; r < 4; ++r) {
                int ml = pm * 128 + fm * 16 + lq * 4 + r;
                int m  = bm0 + ml;
                float dv = distS[ml * 8 + 7];
#pragma unroll
                for (int fn = 0; fn < 4; ++fn) {
                    f32x4 other = *(const f32x4*)&dump[((fm * 4 + fn) * 64 + lane) * 4];
                    int col = bn0 + pn * 64 + fn * 16 + lr;
                    Cp[(size_t)m * W_DIM + col] =
                        (acc[fm][fn][r] + other[r]) * dv;
                }
            }
    }
}

// ---------------- kernel 3: split reduction --------------------------------
__global__ __launch_bounds__(256) void k_reduce(
    const float* __restrict__ part, float* __restrict__ out, int nsplit)
{
    int i = (blockIdx.x * 256 + threadIdx.x) * 4;
    f32x4 s = *(const f32x4*)(part + i);
    for (int p = 1; p < nsplit; ++p)
        s += *(const f32x4*)(part + (size_t)p * (B_ROWS * W_DIM) + i);
    *(f32x4*)(out + i) = s;
}

// ---------------- fallback GEMM (single-split, direct to out) --------------
__global__ __launch_bounds__(256, 2) void k_gemm_bt(
    const float* __restrict__ x, const float* __restrict__ dist,
    const unsigned short* __restrict__ Tt, float* __restrict__ part,
    int kchunk)
{
    __shared__ unsigned short As[128][72];
    __shared__ unsigned short Bs[128][64];

    const int bm0 = blockIdx.x * 128;
    const int bn0 = blockIdx.y * 128;
    const int kbase = blockIdx.z * kchunk;

    const int lane = threadIdx.x & 63;
    const int wid  = threadIdx.x >> 6;
    const int wm = wid >> 1, wn = wid & 1;
    const int lq = lane >> 4, lr = lane & 15;

    f32x4 acc[4][4];
#pragma unroll
    for (int a = 0; a < 4; ++a)
#pragma unroll
        for (int b = 0; b < 4; ++b)
            acc[a][b] = (f32x4){0.f, 0.f, 0.f, 0.f};

    const int iters = kchunk / 64;
    for (int it = 0; it < iters; ++it) {
        const int k0 = kbase + it * 64;
        const int l  = k0 >> 9;
        const int i0 = k0 & 511;
#pragma unroll
        for (int r2 = 0; r2 < 8; ++r2) {
            int id = threadIdx.x + r2 * 256;
            int m  = id >> 4;
            int kc = id & 15;
            float sc = dist[(size_t)(bm0 + m) * N_BINS + l];
            f32x4 v = *(const f32x4*)(x + (size_t)(bm0 + m) * D_DIM + i0 + kc * 4);
            v *= sc;
            unsigned int p0 = (unsigned int)f2bf(v.x) | ((unsigned int)f2bf(v.y) << 16);
            unsigned int p1 = (unsigned int)f2bf(v.z) | ((unsigned int)f2bf(v.w) << 16);
            unsigned int* dp = (unsigned int*)&As[m][kc * 4];
            dp[0] = p0; dp[1] = p1;
        }
#pragma unroll
        for (int r2 = 0; r2 < 4; ++r2) {
            int id = threadIdx.x + r2 * 256;
            int n  = id >> 3;
            int cc = id & 7;
            int cg = cc ^ (n & 7);
            const u16x8 v = *(const u16x8*)(Tt + (size_t)(bn0 + n) * K_TOT + k0 + cg * 8);
            *(u16x8*)&Bs[n][cc * 8] = v;
        }
        __syncthreads();
#pragma unroll
        for (int ks = 0; ks < 2; ++ks) {
            bf16x8 af[4], bfr[4];
#pragma unroll
            for (int fm = 0; fm < 4; ++fm)
                af[fm] = *(const bf16x8*)&As[wm * 64 + fm * 16 + lr][ks * 32 + lq * 8];
#pragma unroll
            for (int fn = 0; fn < 4; ++fn) {
                int nl = wn * 64 + fn * 16 + lr;
                int cs = (ks * 4 + lq) ^ (nl & 7);
                bfr[fn] = *(const bf16x8*)&Bs[nl][cs * 8];
            }
#pragma unroll
            for (int fm = 0; fm < 4; ++fm)
#pragma unroll
                for (int fn = 0; fn < 4; ++fn)
                    acc[fm][fn] = __builtin_amdgcn_mfma_f32_16x16x32_bf16(
                        af[fm], bfr[fn], acc[fm][fn], 0, 0, 0);
        }
        __syncthreads();
    }

    float* Cp = part + (size_t)blockIdx.z * (B_ROWS * W_DIM);
#pragma unroll
    for (int fm = 0; fm < 4; ++fm)
#pragma unroll
        for (int fn = 0; fn < 4; ++fn)
#pragma unroll
            for (int r = 0; r < 4; ++r) {
                int row = bm0 + wm * 64 + fm * 16 + lq * 4 + r;
                int col = bn0 + wn * 64 + fn * 16 + lr;
                Cp[(size_t)row * W_DIM + col] = acc[fm][fn][r];
            }
}

extern "C" void kernel_launch(void* const* d_in, const int* in_sizes, int n_in,
                              void* d_out, int out_size, void* d_ws, size_t ws_size,
                              hipStream_t stream) {
    const float* x   = (const float*)d_in[0];
    const float* ray = (const float*)d_in[1];
    const float* w_i = (const float*)d_in[2];
    const float* b_i = (const float*)d_in[3];
    const float* a_i = (const float*)d_in[4];
    const float* T   = (const float*)d_in[5];
    const int*   idx = (const int*)d_in[6];
    float* out = (float*)d_out;

    char* ws = (char*)d_ws;
    const size_t distBytes = (size_t)B_ROWS * N_BINS * 4;        // 512 KiB
    const size_t xbBytes   = (size_t)B_ROWS * D_DIM * 2;         // 2 MiB
    const size_t ttBytes   = (size_t)W_DIM * K_TOT * 2;          // 32 MiB
    const size_t partBytes = (size_t)B_ROWS * W_DIM * 4;         // 4 MiB per split

    float*          dist = (float*)ws;
    unsigned short* xb   = (unsigned short*)(ws + distBytes);
    unsigned short* Tt   = (unsigned short*)(ws + distBytes + xbBytes);

    if (ws_size >= distBytes + xbBytes + ttBytes + (size_t)NSPLIT * partBytes) {
        // -------- path A: wave-pair split-K, 1-barrier schedule, NSPLIT=8 --
        float* part = (float*)(ws + distBytes + xbBytes + ttBytes);

        k_pre<<<4096 + 512, 256, 0, stream>>>(x, ray, w_i, b_i, a_i, idx, T,
                                              dist, xb, Tt);
        k_gemm13<<<256, 512, 0, stream>>>(xb, Tt, dist, part);
        k_reduce<<<(B_ROWS * W_DIM) / (256 * 4), 256, 0, stream>>>(part, out, NSPLIT);
    } else if (ws_size >= distBytes + xbBytes + ttBytes) {
        // -------- path B: single-split direct-to-out --------
        k_pre<<<4096 + 512, 256, 0, stream>>>(x, ray, w_i, b_i, a_i, idx, T,
                                              dist, xb, Tt);
        k_gemm_bt<<<dim3(16, 4, 1), 256, 0, stream>>>(x, dist, Tt, out, K_TOT);
    }
}

// Round 5
// 189.847 us; speedup vs baseline: 1.1461x; 1.0013x over previous
//
#include <hip/hip_runtime.h>
#include <math.h>

typedef float  f32x4  __attribute__((ext_vector_type(4)));
typedef float  f32x2  __attribute__((ext_vector_type(2)));
typedef short  bf16x8 __attribute__((ext_vector_type(8)));
typedef unsigned short u16x8 __attribute__((ext_vector_type(8)));
typedef unsigned short u16x4 __attribute__((ext_vector_type(4)));

#define B_ROWS 2048
#define D_DIM  512
#define W_DIM  512
#define N_NODES 63
#define N_BINS  64
#define K_TOT   32768   // 64 * 512
#define DEPS    1e-12f

#define STR2(x) #x
#define WAITVM(n) asm volatile("s_waitcnt vmcnt(" STR2(n) ")" ::: "memory")

__device__ __forceinline__ unsigned short f2bf(float f) {
    union { float f; unsigned int u; } v; v.f = f;
    unsigned int u = v.u;
    return (unsigned short)((u + 0x7fffu + ((u >> 16) & 1u)) >> 16);
}

__device__ __forceinline__ float sigmoidf_(float z) {
    return 1.0f / (1.0f + expf(-z));
}

__device__ __forceinline__ void load_lds16(const void* g, void* l) {
    __builtin_amdgcn_global_load_lds(
        (const __attribute__((address_space(1))) unsigned int*)g,
        (__attribute__((address_space(3))) unsigned int*)l,
        16, 0, 0);
}

// ---------------- kernel 1: fused prep (dist + xb) AND transpose -----------
__global__ __launch_bounds__(256) void k_pre(
    const float* __restrict__ x, const float* __restrict__ ray,
    const float* __restrict__ w_i, const float* __restrict__ b_i,
    const float* __restrict__ a_i, const int* __restrict__ idx,
    const float* __restrict__ T,
    float* __restrict__ dist, unsigned short* __restrict__ xb,
    unsigned short* __restrict__ Tt)
{
    __shared__ float tile[64][65];
    const int bid = blockIdx.x;
    const int t   = threadIdx.x;

    if (bid < 4096) {
        const int i0 = (bid & 7) * 64;
        const int w0 = ((bid >> 3) & 7) * 64;
        const int l  = bid >> 6;

        const int w4 = (t & 15) * 4;
        const int ir = t >> 4;
        const float* src = T + ((size_t)(l * 512 + i0)) * 512 + w0;
#pragma unroll
        for (int p = 0; p < 4; ++p) {
            int i = ir + p * 16;
            f32x4 v = *(const f32x4*)(src + (size_t)i * 512 + w4);
            tile[i][w4 + 0] = v.x; tile[i][w4 + 1] = v.y;
            tile[i][w4 + 2] = v.z; tile[i][w4 + 3] = v.w;
        }
        __syncthreads();
#pragma unroll
        for (int rep = 0; rep < 2; ++rep) {
            int id = t + rep * 256;
            int w  = id >> 3;
            int c  = id & 7;
            u16x8 o;
#pragma unroll
            for (int j = 0; j < 8; ++j) o[j] = f2bf(tile[c * 8 + j][w]);
            *(u16x8*)(Tt + (size_t)(w0 + w) * K_TOT + l * 512 + i0 + c * 8) = o;
        }
        return;
    }

    const int pb   = bid - 4096;
    const int wid  = t >> 6;
    const int lane = t & 63;
    const int row  = pb * 4 + wid;
    const float* xr = x + (size_t)row * D_DIM;

    float dotv = 0.f, xx = 0.f, rr = 0.f;
#pragma unroll
    for (int j = 0; j < 2; ++j) {
        f32x4 xv = *(const f32x4*)(xr  + j * 256 + lane * 4);
        f32x4 rv = *(const f32x4*)(ray + j * 256 + lane * 4);
        dotv += xv.x * rv.x + xv.y * rv.y + xv.z * rv.z + xv.w * rv.w;
        xx   += xv.x * xv.x + xv.y * xv.y + xv.z * xv.z + xv.w * xv.w;
        rr   += rv.x * rv.x + rv.y * rv.y + rv.z * rv.z + rv.w * rv.w;
        u16x4 o;
        o[0] = f2bf(xv.x); o[1] = f2bf(xv.y); o[2] = f2bf(xv.z); o[3] = f2bf(xv.w);
        *(u16x4*)(xb + (size_t)row * D_DIM + j * 256 + lane * 4) = o;
    }
#pragma unroll
    for (int off = 1; off < 64; off <<= 1) {
        dotv += __shfl_xor(dotv, off, 64);
        xx   += __shfl_xor(xx,   off, 64);
        rr   += __shfl_xor(rr,   off, 64);
    }
    float xn = fmaxf(sqrtf(xx), 1e-8f);
    float rn = fmaxf(sqrtf(rr), 1e-8f);
    float cosv = dotv / (xn * rn);
    cosv = fminf(1.f, fmaxf(-1.f, cosv));
    float angle = acosf(cosv) * 0.31830988618379067f;

    float dec = 0.f;
    if (lane < N_NODES) {
        float sw = sigmoidf_(w_i[lane]);
        float sb = sigmoidf_(b_i[lane]);
        float nf = (0.5f + sw) * angle - sb;
        dec = sigmoidf_(nf * (1.0f + a_i[lane]));
    }

    float p = 1.f;
#pragma unroll
    for (int v = 0; v < 6; ++v) {
        int j = idx[lane * 6 + v];
        int node = (j < N_NODES) ? j : j - N_NODES;
        float d = __shfl(dec, node, 64);
        p *= (j < N_NODES) ? d : (1.0f - d);
    }
    dist[(size_t)row * N_BINS + lane] = p;
}

// ---------------- kernel 2a: 256x256 4-phase template GEMM (NSPLIT=16) -----
// m201-style schedule adapted: BM=BN=256, BK=64, 8 waves (2M x 4N),
// per-wave 128x64 C. Interleaved row mapping (m = fm*32 + wm*16,
// n = fn*64 + wn*16) aligns each phase's operand set with ONE staged
// half-tile, so per-phase counted vmcnt(4) is exact: each phase waits
// only for the half it consumes; 2-3 half-tiles always in flight,
// vmcnt never drains to 0 in the loop. Per phase: ds-reads -> stage one
// half -> barrier -> lgkmcnt(0) -> setprio(1) 16 MFMA setprio(0) ->
// vmcnt -> barrier. dist slab staged linear to LDS (oldest load).
__global__ __launch_bounds__(512, 2) void k_gemm16(
    const unsigned short* __restrict__ xb, const unsigned short* __restrict__ Tt,
    const float* __restrict__ dist, float* __restrict__ part)
{
    __shared__ unsigned short As[2][256 * 64];   // 64 KB
    __shared__ unsigned short Bs[2][256 * 64];   // 64 KB
    __shared__ float distS[256 * 4];             // 4 KB   (132 KB total)

    const int b    = blockIdx.x;          // 0..255
    const int xcd  = b & 7;
    const int g    = b >> 3;              // 0..31
    const int z    = xcd * 2 + (g & 1);   // 0..15  (2 K-splits per XCD)
    const int tile = g >> 1;              // 0..15
    const int bm0  = (tile & 7) * 256;
    const int bn0  = (tile >> 3) * 256;
    const int l0   = z * 4;               // LPS = 4

    const int t    = threadIdx.x;         // 0..511
    const int lane = t & 63;
    const int wid  = t >> 6;              // 0..7
    const int wm   = wid >> 2;            // 0..1
    const int wn   = wid & 3;             // 0..3
    const int lq = lane >> 4, lr = lane & 15;

    const int srow = t >> 3;              // 0..63
    const int c    = t & 7;

    f32x4 acc[8][4];
#pragma unroll
    for (int a = 0; a < 8; ++a)
#pragma unroll
        for (int bb = 0; bb < 4; ++bb)
            acc[a][bb] = (f32x4){0.f, 0.f, 0.f, 0.f};

#define SGA(u_, slot_, g_)                                                    \
    {                                                                         \
        const int i0_  = ((u_) & 7) * 64;                                     \
        const int row_ = srow + (g_) * 64;                                    \
        const int cg_  = c ^ (row_ & 7);                                      \
        load_lds16(xb + (size_t)(bm0 + row_) * D_DIM + i0_ + cg_ * 8,         \
                   &As[slot_][row_ * 64 + c * 8]);                            \
    }
#define SGB(u_, slot_, g_)                                                    \
    {                                                                         \
        const int l_   = l0 + ((u_) >> 3);                                    \
        const int i0_  = ((u_) & 7) * 64;                                     \
        const int row_ = srow + (g_) * 64;                                    \
        const int cg_  = c ^ (row_ & 7);                                      \
        load_lds16(Tt + (size_t)(bn0 + row_) * K_TOT + (size_t)l_ * 512       \
                       + i0_ + cg_ * 8,                                       \
                   &Bs[slot_][row_ * 64 + c * 8]);                            \
    }

#define RD_A(dst, fmb)                                                        \
    _Pragma("unroll") for (int f = 0; f < 4; ++f)                             \
    _Pragma("unroll") for (int ks = 0; ks < 2; ++ks) {                        \
        int row = ((fmb) + f) * 32 + wm * 16 + lr;                            \
        dst[f][ks] = *(const bf16x8*)&As[rs][row * 64 +                       \
                       (((ks * 4 + lq) ^ (row & 7)) * 8)];                    \
    }
#define RD_B(dst, fnb)                                                        \
    _Pragma("unroll") for (int f = 0; f < 2; ++f)                             \
    _Pragma("unroll") for (int ks = 0; ks < 2; ++ks) {                        \
        int row = ((fnb) + f) * 64 + wn * 16 + lr;                            \
        dst[f][ks] = *(const bf16x8*)&Bs[rs][row * 64 +                       \
                       (((ks * 4 + lq) ^ (row & 7)) * 8)];                    \
    }
#define MM(fmb, afv, bfv, fnb)                                                \
    __builtin_amdgcn_s_setprio(1);                                            \
    _Pragma("unroll") for (int f = 0; f < 4; ++f)                             \
    _Pragma("unroll") for (int e = 0; e < 2; ++e)                             \
    _Pragma("unroll") for (int ks = 0; ks < 2; ++ks)                          \
        acc[(fmb) + f][(fnb) + e] = __builtin_amdgcn_mfma_f32_16x16x32_bf16(  \
            afv[f][ks], bfv[e][ks], acc[(fmb) + f][(fnb) + e], 0, 0, 0);      \
    __builtin_amdgcn_s_setprio(0);

#define LGKM0                                                                 \
    asm volatile("s_waitcnt lgkmcnt(0)" ::: "memory");                        \
    __builtin_amdgcn_sched_barrier(0);

// One BK=64 tile: 4 phases. Stage order for tile u+1: A0,B0,B1,A1 (matches
// consumption order at u+1: P0 needs A0+B0, P1 needs B1, P2 needs A1).
// V0_/V1_ are the counted vmcnt at ends of P0/P1; P3 always ends vmcnt(4)
// (no-op on the final tile where nothing is outstanding).
#define TILE(u_, V0_, V1_, PF_)                                               \
  {                                                                           \
    const int rs = (u_) & 1, ss = rs ^ 1;                                     \
    /* P0: fmL x fn{0,1} */                                                   \
    RD_A(afr, 0) RD_B(bfr0, 0)                                                \
    if (PF_) { SGA((u_) + 1, ss, 0) SGA((u_) + 1, ss, 1) }                    \
    __builtin_amdgcn_s_barrier();                                             \
    LGKM0                                                                     \
    MM(0, afr, bfr0, 0)                                                       \
    WAITVM(V0_);                                                              \
    __builtin_amdgcn_s_barrier();                                             \
    /* P1: fmL x fn{2,3} */                                                   \
    RD_B(bfr1, 2)                                                             \
    if (PF_) { SGB((u_) + 1, ss, 0) SGB((u_) + 1, ss, 1) }                    \
    __builtin_amdgcn_s_barrier();                                             \
    LGKM0                                                                     \
    MM(0, afr, bfr1, 2)                                                       \
    WAITVM(V1_);                                                              \
    __builtin_amdgcn_s_barrier();                                             \
    /* P2: fmH x fn{0,1} */                                                   \
    RD_A(afr, 4)                                                              \
    if (PF_) { SGB((u_) + 1, ss, 2) SGB((u_) + 1, ss, 3) }                    \
    __builtin_amdgcn_s_barrier();                                             \
    LGKM0                                                                     \
    MM(4, afr, bfr0, 0)                                                       \
    __builtin_amdgcn_s_barrier();                                             \
    /* P3: fmH x fn{2,3} */                                                   \
    if (PF_) { SGA((u_) + 1, ss, 2) SGA((u_) + 1, ss, 3) }                    \
    __builtin_amdgcn_s_barrier();                                             \
    __builtin_amdgcn_sched_barrier(0);                                        \
    MM(4, afr, bfr1, 2)                                                       \
    WAITVM(4);                                                                \
    __builtin_amdgcn_s_barrier();                                             \
  }

    bf16x8 afr[4][2], bfr0[2][2], bfr1[2][2];

    // prologue: dist slab (oldest), then tile0 halves A0,B0,B1,A1.
    if (t < 256)
        load_lds16(dist + (size_t)(bm0 + t) * N_BINS + l0, &distS[t * 4]);
    SGA(0, 0, 0) SGA(0, 0, 1)
    SGB(0, 0, 0) SGB(0, 0, 1)
    SGB(0, 0, 2) SGB(0, 0, 3)
    SGA(0, 0, 2) SGA(0, 0, 3)
    WAITVM(4);                 // dist + A0 + B0 landed; B1,A1 in flight
    __builtin_amdgcn_s_barrier();

    for (int u = 0; u < 31; ++u) {
        if ((u & 7) == 0 && u > 0) {
            const int li = (u >> 3) - 1;   // 0..2
#pragma unroll
            for (int fm = 0; fm < 8; ++fm)
#pragma unroll
                for (int r = 0; r < 4; ++r) {
                    int ml = fm * 32 + wm * 16 + lq * 4 + r;
                    float dp = fmaxf(distS[ml * 4 + li],     DEPS);
                    float dn = fmaxf(distS[ml * 4 + li + 1], DEPS);
                    float ratio = dp * __builtin_amdgcn_rcpf(dn);
#pragma unroll
                    for (int fn = 0; fn < 4; ++fn)
                        acc[fm][fn][r] *= ratio;
                }
        }
        TILE(u, 4, 4, true)
    }
    TILE(31, 2, 0, false)

#undef TILE
#undef LGKM0
#undef MM
#undef RD_A
#undef RD_B
#undef SGA
#undef SGB

    // epilogue: fold d[l0+3] and store partial
    float* Cp = part + (size_t)z * (B_ROWS * W_DIM);
#pragma unroll
    for (int fm = 0; fm < 8; ++fm)
#pragma unroll
        for (int r = 0; r < 4; ++r) {
            int ml = fm * 32 + wm * 16 + lq * 4 + r;
            float dv = fmaxf(distS[ml * 4 + 3], DEPS);
            int m = bm0 + ml;
#pragma unroll
            for (int fn = 0; fn < 4; ++fn) {
                int col = bn0 + fn * 64 + wn * 16 + lr;
                Cp[(size_t)m * W_DIM + col] = acc[fm][fn][r] * dv;
            }
        }
}

// ---------------- kernel 2b: round-1 proven GEMM (NSPLIT=8 fallback) -------
__global__ __launch_bounds__(512, 2) void k_gemm10(
    const unsigned short* __restrict__ xb, const unsigned short* __restrict__ Tt,
    const float* __restrict__ dist, float* __restrict__ part)
{
    __shared__ unsigned short As[3][256 * 64];   // 96 KB
    __shared__ unsigned short Bs[3][128 * 64];   // 48 KB

    const int b    = blockIdx.x;          // 0..255
    const int z    = b & 7;               // split == XCD
    const int tile = b >> 3;              // 0..31
    const int bm0  = (tile & 7) * 256;
    const int bn0  = (tile >> 3) * 128;
    const int l0   = z * 8;

    const int t    = threadIdx.x;         // 0..511
    const int lane = t & 63;
    const int wid  = t >> 6;              // 0..7
    const int wm = wid >> 1, wn = wid & 1;
    const int lq = lane >> 4, lr = lane & 15;

    const int srow = t >> 3;              // 0..63
    const int c    = t & 7;

    f32x4 acc[4][4];
#pragma unroll
    for (int a = 0; a < 4; ++a)
#pragma unroll
        for (int bb = 0; bb < 4; ++bb)
            acc[a][bb] = (f32x4){0.f, 0.f, 0.f, 0.f};

#define STAGE_A(u_, slot_, g_)                                                \
    {                                                                         \
        const int i0_  = ((u_) & 7) * 64;                                     \
        const int row_ = srow + (g_) * 64;                                    \
        const int cg_  = c ^ (row_ & 7);                                      \
        load_lds16(xb + (size_t)(bm0 + row_) * D_DIM + i0_ + cg_ * 8,         \
                   &As[slot_][row_ * 64 + c * 8]);                            \
    }
#define STAGE_B(u_, slot_, g_)                                                \
    {                                                                         \
        const int l_   = l0 + ((u_) >> 3);                                    \
        const int i0_  = ((u_) & 7) * 64;                                     \
        const int row_ = srow + (g_) * 64;                                    \
        const int cg_  = c ^ (row_ & 7);                                      \
        load_lds16(Tt + (size_t)(bn0 + row_) * K_TOT + (size_t)l_ * 512       \
                       + i0_ + cg_ * 8,                                       \
                   &Bs[slot_][row_ * 64 + c * 8]);                            \
    }

    STAGE_A(0, 0, 0) STAGE_A(0, 0, 1) STAGE_A(0, 0, 2) STAGE_A(0, 0, 3)
    STAGE_B(0, 0, 0) STAGE_B(0, 0, 1)
    STAGE_A(1, 1, 0) STAGE_A(1, 1, 1) STAGE_A(1, 1, 2) STAGE_A(1, 1, 3)
    STAGE_B(1, 1, 0) STAGE_B(1, 1, 1)

    int rs = 0;
    for (int u = 0; u < 64; ++u) {
        if (u < 63) WAITVM(6);
        else        WAITVM(0);
        __builtin_amdgcn_s_barrier();

        if ((u & 7) == 0 && u > 0) {
            const int l = l0 + (u >> 3);
#pragma unroll
            for (int fm = 0; fm < 4; ++fm)
#pragma unroll
                for (int r = 0; r < 4; ++r) {
                    int m = bm0 + wm * 64 + fm * 16 + lq * 4 + r;
                    f32x2 dd = *(const f32x2*)(dist + (size_t)m * N_BINS + (l - 1));
                    float dp = fmaxf(dd.x, DEPS);
                    float dn = fmaxf(dd.y, DEPS);
                    float ratio = dp * __builtin_amdgcn_rcpf(dn);
#pragma unroll
                    for (int fn = 0; fn < 4; ++fn)
                        acc[fm][fn][r] *= ratio;
                }
        }

        const int ws_ = (rs == 0) ? 2 : rs - 1;
        const bool pf = (u + 2 < 64);

        {
            bf16x8 af[4], bfv[4];
#pragma unroll
            for (int fm = 0; fm < 4; ++fm) {
                int m = wm * 64 + fm * 16 + lr;
                af[fm] = *(const bf16x8*)&As[rs][m * 64 + ((lq ^ (m & 7)) * 8)];
            }
#pragma unroll
            for (int fn = 0; fn < 4; ++fn) {
                int n = wn * 64 + fn * 16 + lr;
                bfv[fn] = *(const bf16x8*)&Bs[rs][n * 64 + ((lq ^ (n & 7)) * 8)];
            }
            if (pf) { STAGE_A(u + 2, ws_, 0) STAGE_A(u + 2, ws_, 1) STAGE_A(u + 2, ws_, 2) }
            __builtin_amdgcn_s_setprio(1);
#pragma unroll
            for (int fm = 0; fm < 4; ++fm)
#pragma unroll
                for (int fn = 0; fn < 4; ++fn)
                    acc[fm][fn] = __builtin_amdgcn_mfma_f32_16x16x32_bf16(
                        af[fm], bfv[fn], acc[fm][fn], 0, 0, 0);
            __builtin_amdgcn_s_setprio(0);
        }
        __builtin_amdgcn_s_barrier();
        {
            bf16x8 af[4], bfv[4];
#pragma unroll
            for (int fm = 0; fm < 4; ++fm) {
                int m = wm * 64 + fm * 16 + lr;
                af[fm] = *(const bf16x8*)&As[rs][m * 64 + (((4 + lq) ^ (m & 7)) * 8)];
            }
#pragma unroll
            for (int fn = 0; fn < 4; ++fn) {
                int n = wn * 64 + fn * 16 + lr;
                bfv[fn] = *(const bf16x8*)&Bs[rs][n * 64 + (((4 + lq) ^ (n & 7)) * 8)];
            }
            if (pf) { STAGE_A(u + 2, ws_, 3) STAGE_B(u + 2, ws_, 0) STAGE_B(u + 2, ws_, 1) }
            __builtin_amdgcn_s_setprio(1);
#pragma unroll
            for (int fm = 0; fm < 4; ++fm)
#pragma unroll
                for (int fn = 0; fn < 4; ++fn)
                    acc[fm][fn] = __builtin_amdgcn_mfma_f32_16x16x32_bf16(
                        af[fm], bfv[fn], acc[fm][fn], 0, 0, 0);
            __builtin_amdgcn_s_setprio(0);
        }

        rs = (rs == 2) ? 0 : rs + 1;
    }
#undef STAGE_A
#undef STAGE_B

    float* Cp = part + (size_t)z * (B_ROWS * W_DIM);
#pragma unroll
    for (int fm = 0; fm < 4; ++fm)
#pragma unroll
        for (int r = 0; r < 4; ++r) {
            int m = bm0 + wm * 64 + fm * 16 + lq * 4 + r;
            float dl = fmaxf(dist[(size_t)m * N_BINS + (l0 + 7)], DEPS);
#pragma unroll
            for (int fn = 0; fn < 4; ++fn) {
                int col = bn0 + wn * 64 + fn * 16 + lr;
                Cp[(size_t)m * W_DIM + col] = acc[fm][fn][r] * dl;
            }
        }
}

// ---------------- kernel 3: split reduction --------------------------------
__global__ __launch_bounds__(256) void k_reduce(
    const float* __restrict__ part, float* __restrict__ out, int nsplit)
{
    int i = (blockIdx.x * 256 + threadIdx.x) * 4;
    f32x4 s = *(const f32x4*)(part + i);
    for (int p = 1; p < nsplit; ++p)
        s += *(const f32x4*)(part + (size_t)p * (B_ROWS * W_DIM) + i);
    *(f32x4*)(out + i) = s;
}

// ---------------- fallback GEMM (single-split, direct to out) --------------
__global__ __launch_bounds__(256, 2) void k_gemm_bt(
    const float* __restrict__ x, const float* __restrict__ dist,
    const unsigned short* __restrict__ Tt, float* __restrict__ part,
    int kchunk)
{
    __shared__ unsigned short As[128][72];
    __shared__ unsigned short Bs[128][64];

    const int bm0 = blockIdx.x * 128;
    const int bn0 = blockIdx.y * 128;
    const int kbase = blockIdx.z * kchunk;

    const int lane = threadIdx.x & 63;
    const int wid  = threadIdx.x >> 6;
    const int wm = wid >> 1, wn = wid & 1;
    const int lq = lane >> 4, lr = lane & 15;

    f32x4 acc[4][4];
#pragma unroll
    for (int a = 0; a < 4; ++a)
#pragma unroll
        for (int b = 0; b < 4; ++b)
            acc[a][b] = (f32x4){0.f, 0.f, 0.f, 0.f};

    const int iters = kchunk / 64;
    for (int it = 0; it < iters; ++it) {
        const int k0 = kbase + it * 64;
        const int l  = k0 >> 9;
        const int i0 = k0 & 511;
#pragma unroll
        for (int r2 = 0; r2 < 8; ++r2) {
            int id = threadIdx.x + r2 * 256;
            int m  = id >> 4;
            int kc = id & 15;
            float sc = dist[(size_t)(bm0 + m) * N_BINS + l];
            f32x4 v = *(const f32x4*)(x + (size_t)(bm0 + m) * D_DIM + i0 + kc * 4);
            v *= sc;
            unsigned int p0 = (unsigned int)f2bf(v.x) | ((unsigned int)f2bf(v.y) << 16);
            unsigned int p1 = (unsigned int)f2bf(v.z) | ((unsigned int)f2bf(v.w) << 16);
            unsigned int* dp = (unsigned int*)&As[m][kc * 4];
            dp[0] = p0; dp[1] = p1;
        }
#pragma unroll
        for (int r2 = 0; r2 < 4; ++r2) {
            int id = threadIdx.x + r2 * 256;
            int n  = id >> 3;
            int cc = id & 7;
            int cg = cc ^ (n & 7);
            const u16x8 v = *(const u16x8*)(Tt + (size_t)(bn0 + n) * K_TOT + k0 + cg * 8);
            *(u16x8*)&Bs[n][cc * 8] = v;
        }
        __syncthreads();
#pragma unroll
        for (int ks = 0; ks < 2; ++ks) {
            bf16x8 af[4], bfr[4];
#pragma unroll
            for (int fm = 0; fm < 4; ++fm)
                af[fm] = *(const bf16x8*)&As[wm * 64 + fm * 16 + lr][ks * 32 + lq * 8];
#pragma unroll
            for (int fn = 0; fn < 4; ++fn) {
                int nl = wn * 64 + fn * 16 + lr;
                int cs = (ks * 4 + lq) ^ (nl & 7);
                bfr[fn] = *(const bf16x8*)&Bs[nl][cs * 8];
            }
#pragma unroll
            for (int fm = 0; fm < 4; ++fm)
#pragma unroll
                for (int fn = 0; fn < 4; ++fn)
                    acc[fm][fn] = __builtin_amdgcn_mfma_f32_16x16x32_bf16(
                        af[fm], bfr[fn], acc[fm][fn], 0, 0, 0);
        }
        __syncthreads();
    }

    float* Cp = part + (size_t)blockIdx.z * (B_ROWS * W_DIM);
#pragma unroll
    for (int fm = 0; fm < 4; ++fm)
#pragma unroll
        for (int fn = 0; fn < 4; ++fn)
#pragma unroll
            for (int r = 0; r < 4; ++r) {
                int row = bm0 + wm * 64 + fm * 16 + lq * 4 + r;
                int col = bn0 + wn * 64 + fn * 16 + lr;
                Cp[(size_t)row * W_DIM + col] = acc[fm][fn][r];
            }
}

extern "C" void kernel_launch(void* const* d_in, const int* in_sizes, int n_in,
                              void* d_out, int out_size, void* d_ws, size_t ws_size,
                              hipStream_t stream) {
    const float* x   = (const float*)d_in[0];
    const float* ray = (const float*)d_in[1];
    const float* w_i = (const float*)d_in[2];
    const float* b_i = (const float*)d_in[3];
    const float* a_i = (const float*)d_in[4];
    const float* T   = (const float*)d_in[5];
    const int*   idx = (const int*)d_in[6];
    float* out = (float*)d_out;

    char* ws = (char*)d_ws;
    const size_t distBytes = (size_t)B_ROWS * N_BINS * 4;        // 512 KiB
    const size_t xbBytes   = (size_t)B_ROWS * D_DIM * 2;         // 2 MiB
    const size_t ttBytes   = (size_t)W_DIM * K_TOT * 2;          // 32 MiB
    const size_t partBytes = (size_t)B_ROWS * W_DIM * 4;         // 4 MiB per split

    float*          dist = (float*)ws;
    unsigned short* xb   = (unsigned short*)(ws + distBytes);
    unsigned short* Tt   = (unsigned short*)(ws + distBytes + xbBytes);
    float*          part = (float*)(ws + distBytes + xbBytes + ttBytes);

    const size_t base   = distBytes + xbBytes + ttBytes;
    const size_t need16 = base + 16 * partBytes;   // 98.5 MiB
    const size_t need8  = base + 8 * partBytes;    // 66.5 MiB

    if (ws_size >= need16) {
        // -------- path A16: 256x256 4-phase template, NSPLIT=16 --------
        k_pre<<<4096 + 512, 256, 0, stream>>>(x, ray, w_i, b_i, a_i, idx, T,
                                              dist, xb, Tt);
        k_gemm16<<<256, 512, 0, stream>>>(xb, Tt, dist, part);
        k_reduce<<<(B_ROWS * W_DIM) / (256 * 4), 256, 0, stream>>>(part, out, 16);
    } else if (ws_size >= need8) {
        // -------- path A8: round-1 proven counted-vmcnt GEMM, NSPLIT=8 --
        k_pre<<<4096 + 512, 256, 0, stream>>>(x, ray, w_i, b_i, a_i, idx, T,
                                              dist, xb, Tt);
        k_gemm10<<<256, 512, 0, stream>>>(xb, Tt, dist, part);
        k_reduce<<<(B_ROWS * W_DIM) / (256 * 4), 256, 0, stream>>>(part, out, 8);
    } else if (ws_size >= base) {
        // -------- path B: single-split direct-to-out --------
        k_pre<<<4096 + 512, 256, 0, stream>>>(x, ray, w_i, b_i, a_i, idx, T,
                                              dist, xb, Tt);
        k_gemm_bt<<<dim3(16, 4, 1), 256, 0, stream>>>(x, dist, Tt, out, K_TOT);
    }
}